// Round 9
// baseline (482.442 us; speedup 1.0000x reference)
//
#include <hip/hip_runtime.h>
#include <math.h>

#define B_ 8
#define L_ 2048
#define DM 6
#define ED 48
#define NS 32
#define DCONV 16
#define NLAYERS 4
#define NCLASSES 4
#define EPS 1e-5f

#define NBLK 2048              // 8 blocks/CU co-resident (persistent, max waves)
#define TILEW 16
#define NTILE (L_ / TILEW)     // 128 pre-tiles per batch
#define NSPAN 32
#define SPANL (L_ / NSPAN)     // 64 steps per scan span

#define EDL (B_ * ED * L_)     // 786432 floats
#define NSL (B_ * L_ * NS)     // 524288
#define DML (B_ * DM * L_)     // 98304
#define SUMSZ (B_ * ED * NSPAN * NS)   // 393216

// Per-layer buffer instances (write-once per execution -> no stale-L1 hazard,
// no cache maintenance needed in XCD-local mode).
// layout per layer: z, xc, delta, y, Bm, Cm, h, sumA, sumH
#define LSTRIDE (4 * EDL + 2 * NSL + DML + 2 * SUMSZ)
#define WS_BAR (NLAYERS * LSTRIDE)     // float offset of barrier area

#define N_EPOCH 12                     // 3 barriers per layer
// u32 layout at ws+WS_BAR: ureg[8][16] | leaves[9][N_EPOCH][4][16] | masters[9][N_EPOCH][16]
#define UREG_OFF 0
#define LEAF_OFF 128
#define MST_OFF (128 + 9 * N_EPOCH * 4 * 16)
#define BAR_U32 (MST_OFF + 9 * N_EPOCH * 16)
#define BAR_BYTES (BAR_U32 * 4)

// ---------------------------------------------------------------------------
// Round-9: final occupancy doubling. Round-8 confirmed the TLP model:
// occupancy 23->46.5% (== the 16-waves/CU residency cap) gave 510->325us,
// VALUBusy 39%, HBM 4%. Still latency-bound at the self-imposed cap.
//  * NBLK 2048 + __launch_bounds__(256,8): 32 waves/CU (hardware max).
//    LDS 10KB x 8 = 80KB OK; VGPR cap 64 == what the compiler already uses.
//  * NSPAN 32 (spans of 64): 1536 scan tasks/XCD so the doubled group-slot
//    count stays fed (at NSPAN=16 only 96/256 blocks would get scan work).
//    Prefix fold <=31 summaries; same telescoped-summary numerics.
// Fence-free XCD-local barriers unchanged (batch b -> XCD b, write-once
// per-layer buffers, relaxed agent atomics only).
// ---------------------------------------------------------------------------

__global__ void __launch_bounds__(256, 8) k_all(
    const float* __restrict__ x,
    const float* __restrict__ in_proj_w,
    const float* __restrict__ conv_w,
    const float* __restrict__ conv_b,
    const float* __restrict__ x_proj_w,
    const float* __restrict__ dt_proj_w,
    const float* __restrict__ dt_proj_b,
    const float* __restrict__ A_log,
    const float* __restrict__ Dp,
    const float* __restrict__ out_proj_w,
    const float* __restrict__ norm_w,
    const float* __restrict__ fc_w,
    const float* __restrict__ fc_b,
    float* __restrict__ out,
    float* __restrict__ ws)
{
    unsigned* bar  = (unsigned*)(ws + WS_BAR);
    unsigned* ureg = bar + UREG_OFF;             // [8][16] per-XCD block counts

    __shared__ float sh[DM][31];     // residual h, 31 positions (l0-15..l0+15)
    __shared__ float sxin[ED][31];   // xin (31 pos)
    __shared__ float sxc[ED][17];    // xc, 16 positions (+1 pad)
    __shared__ float srn[31];        // rms scale per position
    __shared__ float sdr[16];        // dt-rank scalar per position
    __shared__ int s_xcd, s_lidx, s_n, s_mode;

    const int tid = threadIdx.x;

    // ---------------- registration: discover block->XCD mapping ------------
    if (tid == 0) {
        unsigned xcd;
        asm volatile("s_getreg_b32 %0, hwreg(HW_REG_XCC_ID)" : "=s"(xcd));
        xcd &= 7u;
        int lidx0 = (int)__hip_atomic_fetch_add(&ureg[xcd * 16], 1u,
                        __ATOMIC_RELAXED, __HIP_MEMORY_SCOPE_AGENT);
        for (;;) {   // poll sum of per-XCD counters
            unsigned tot = 0;
            for (int xx = 0; xx < 8; ++xx)
                tot += __hip_atomic_load(&ureg[xx * 16], __ATOMIC_RELAXED,
                                         __HIP_MEMORY_SCOPE_AGENT);
            if (tot >= (unsigned)NBLK) break;
            __builtin_amdgcn_s_sleep(1);
        }
        int npres = 0;
        for (int xx = 0; xx < 8; ++xx)
            if (__hip_atomic_load(&ureg[xx * 16], __ATOMIC_RELAXED,
                                  __HIP_MEMORY_SCOPE_AGENT)) npres++;
        s_xcd = (int)xcd; s_lidx = lidx0;
        s_n = (int)__hip_atomic_load(&ureg[xcd * 16], __ATOMIC_RELAXED,
                                     __HIP_MEMORY_SCOPE_AGENT);
        s_mode = (npres == 8) ? 0 : 1;
    }
    __syncthreads();

    const int  mode  = s_mode;                 // 0 = XCD-local, 1 = fallback
    const int  grp   = mode ? 8 : s_xcd;       // barrier group id
    const int  lidx  = mode ? (int)blockIdx.x : s_lidx;
    const int  nwork = mode ? NBLK : s_n;
    const int  b0    = mode ? 0 : s_xcd;       // batches this group owns
    const int  bN    = mode ? B_ : s_xcd + 1;

    // two-level group barrier: 4 leaves + master; counters only in mode 0
    auto gbar = [&](int epoch) {
        __syncthreads();
        if (tid == 0) {
            int lf = lidx & 3;
            unsigned quota = (unsigned)((nwork - lf + 3) >> 2);
            unsigned* leaf = bar + LEAF_OFF
                           + (size_t)((grp * N_EPOCH + epoch) * 4 + lf) * 16;
            unsigned* mst  = bar + MST_OFF
                           + (size_t)(grp * N_EPOCH + epoch) * 16;
            if (mode) __threadfence();
            asm volatile("" ::: "memory");
            if (__hip_atomic_fetch_add(leaf, 1u, __ATOMIC_RELAXED,
                                       __HIP_MEMORY_SCOPE_AGENT) == quota - 1)
                __hip_atomic_fetch_add(mst, 1u, __ATOMIC_RELAXED,
                                       __HIP_MEMORY_SCOPE_AGENT);
            while (__hip_atomic_load(mst, __ATOMIC_RELAXED,
                                     __HIP_MEMORY_SCOPE_AGENT) < 4u)
                __builtin_amdgcn_s_sleep(2);
            asm volatile("" ::: "memory");
            if (mode) __threadfence();
        }
        __syncthreads();
    };

    for (int layer = 0; layer < NLAYERS; ++layer) {
        const float* ipw = in_proj_w + (size_t)layer * 96 * DM;
        const float* nw  = norm_w    + (size_t)layer * DM;
        const float* cw  = conv_w    + (size_t)layer * ED * DCONV;
        const float* cb  = conv_b    + (size_t)layer * ED;
        const float* xpw = x_proj_w  + (size_t)layer * 65 * ED;
        const float* dtw = dt_proj_w + (size_t)layer * ED;
        const float* dtb = dt_proj_b + (size_t)layer * ED;
        const float* al  = A_log     + (size_t)layer * ED * NS;
        const float* dpp = Dp        + (size_t)layer * ED;
        const float* ow  = (layer == 0) ? out_proj_w
                          : out_proj_w + (size_t)(layer - 1) * DM * ED;

        float* Lb    = ws + (size_t)layer * LSTRIDE;
        float* zL    = Lb;
        float* xcL   = zL  + EDL;
        float* dL    = xcL + EDL;
        float* yL    = dL  + EDL;
        float* BmL   = yL  + EDL;                    // [b][l][n]
        float* CmL   = BmL + NSL;                    // [b][l][n]
        float* hL    = CmL + NSL;
        float* saL   = hL  + DML;                    // span summaries exp(A*sum d)
        float* shL   = saL + SUMSZ;                  // span summaries local end h
        const float* hprev = (layer > 0) ? (ws + (size_t)(layer-1) * LSTRIDE
                                            + 4 * EDL + 2 * NSL) : nullptr;
        const float* yprev = (layer > 0) ? (ws + (size_t)(layer-1) * LSTRIDE
                                            + 3 * EDL) : nullptr;

        // ================= PRE: 128 16-wide tiles per batch =================
        for (int bb = b0; bb < bN; ++bb) {
            for (int t = lidx; t < NTILE; t += nwork) {
                const int b  = bb;
                const int l0 = t * TILEW;

                // Phase 1: residual h for 31 positions (15 halo + 16 owned)
                if (layer > 0) {
                    for (int i = tid; i < ED * 31; i += 256) {
                        int e = i / 31, p = i % 31;
                        int l = l0 - 15 + p;
                        sxin[e][p] = (l >= 0)
                            ? yprev[((size_t)b * ED + e) * L_ + l] : 0.f;
                    }
                    __syncthreads();
                    for (int i = tid; i < DM * 31; i += 256) {
                        int d = i / 31, p = i % 31;
                        int l = l0 - 15 + p;
                        float hv = 0.f;
                        if (l >= 0) {
                            hv = hprev[((size_t)b * DM + d) * L_ + l];
                            const float* wp = ow + d * ED;
                            float acc = 0.f;
#pragma unroll
                            for (int e = 0; e < ED; ++e) acc += sxin[e][p] * wp[e];
                            hv += acc;
                            if (p >= 15 && layer < NLAYERS - 1)
                                hL[((size_t)b * DM + d) * L_ + l] = hv;
                        }
                        sh[d][p] = hv;
                    }
                } else {
                    for (int i = tid; i < DM * 31; i += 256) {
                        int d = i / 31, p = i % 31;
                        int l = l0 - 15 + p;
                        float hv = 0.f;
                        if (l >= 0) {
                            hv = x[((size_t)b * L_ + l) * DM + d];
                            if (p >= 15)
                                hL[((size_t)b * DM + d) * L_ + l] = hv;
                        }
                        sh[d][p] = hv;
                    }
                }
                __syncthreads();

                // Phase 2: rms scale per position
                if (tid < 31) {
                    float ss = 0.f;
#pragma unroll
                    for (int d = 0; d < DM; ++d) ss += sh[d][tid] * sh[d][tid];
                    srn[tid] = rsqrtf(ss * (1.f / DM) + EPS);
                }
                __syncthreads();

                // Phase 3a: xin (31 positions, into LDS)
                for (int i = tid; i < ED * 31; i += 256) {
                    int e = i / 31, p = i % 31;
                    const float* wp = ipw + e * DM;
                    float acc = 0.f;
#pragma unroll
                    for (int d = 0; d < DM; ++d) acc += sh[d][p] * nw[d] * wp[d];
                    sxin[e][p] = acc * srn[p];
                }
                // Phase 3b: z (16 owned positions, to global)
                for (int i = tid; i < ED * TILEW; i += 256) {
                    int e = i >> 4, po = i & 15;
                    int p = po + 15;
                    const float* wp = ipw + (ED + e) * DM;
                    float acc = 0.f;
#pragma unroll
                    for (int d = 0; d < DM; ++d) acc += sh[d][p] * nw[d] * wp[d];
                    zL[((size_t)b * ED + e) * L_ + l0 + po] = acc * srn[p];
                }
                __syncthreads();

                // Phase 4: conv + SiLU
                for (int i = tid; i < ED * TILEW; i += 256) {
                    int e = i >> 4, po = i & 15;
                    const float* wp = cw + e * DCONV;
                    float acc = cb[e];
#pragma unroll
                    for (int k = 0; k < DCONV; ++k) acc += sxin[e][po + k] * wp[k];
                    float v = acc / (1.f + __expf(-acc));
                    sxc[e][po] = v;
                    xcL[((size_t)b * ED + e) * L_ + l0 + po] = v;
                }
                __syncthreads();

                // Phase 5: x_proj. 16 output-groups of 4 rows; li = position.
                {
                    int og = tid >> 4, li = tid & 15;
                    int isB = og < 8;
                    int nb = (og & 7) * 4;
                    int rowBase = isB ? (1 + nb) : (1 + NS + nb);
                    const float* wr = xpw + rowBase * ED;
                    float a0=0,a1=0,a2=0,a3=0, dr=0;
#pragma unroll 4
                    for (int e = 0; e < ED; ++e) {
                        float xv = sxc[e][li];
                        a0 += xv * wr[0*ED+e]; a1 += xv * wr[1*ED+e];
                        a2 += xv * wr[2*ED+e]; a3 += xv * wr[3*ED+e];
                        dr += xv * xpw[e];
                    }
                    float* outp = (isB ? BmL : CmL)
                                + ((size_t)(b * L_ + l0 + li)) * NS + nb;
                    *(float4*)outp = make_float4(a0, a1, a2, a3);
                    if (og == 0) sdr[li] = dr;
                }
                __syncthreads();

                // Phase 6: delta = softplus(dr*dtw + dtb)
                for (int i = tid; i < ED * TILEW; i += 256) {
                    int e = i >> 4, po = i & 15;
                    float s = sdr[po] * dtw[e] + dtb[e];
                    dL[((size_t)b * ED + e) * L_ + l0 + po] =
                        fmaxf(s, 0.f) + log1pf(__expf(-fabsf(s)));
                }
                __syncthreads();   // LDS quiescent before next tile
            }
        }
        gbar(layer * 3 + 0);

        // ================= SCAN P1: per-(chain,span) local scan =============
        // task g -> (b, e, span s of 64 steps); 32-lane group per task.
        {
            const int gid = tid >> 5;
            const int n   = tid & 31;
            const int T   = (bN - b0) * ED * NSPAN;
            for (int g = lidx * 8 + gid; g < T; g += nwork * 8) {
                int bb = b0 + g / (ED * NSPAN);
                int r  = g % (ED * NSPAN);
                int e  = r >> 5;
                int s  = r & 31;
                float A = -__expf(al[e * NS + n]);
                size_t eRow = (size_t)(bb * ED + e) * L_ + s * SPANL;
                const float4* dRow = (const float4*)(dL + eRow);
                const float4* xRow = (const float4*)(xcL + eRow);
                const float* bBase = BmL + ((size_t)bb * L_ + s * SPANL) * NS + n;
                float h = 0.f, sd = 0.f;
#pragma unroll 4
                for (int q = 0; q < SPANL / 4; ++q) {
                    float4 d4 = dRow[q];
                    float4 x4 = xRow[q];
                    float v0 = bBase[(4 * q + 0) * NS];
                    float v1 = bBase[(4 * q + 1) * NS];
                    float v2 = bBase[(4 * q + 2) * NS];
                    float v3 = bBase[(4 * q + 3) * NS];
                    h = __expf(d4.x * A) * h + (d4.x * x4.x) * v0;
                    h = __expf(d4.y * A) * h + (d4.y * x4.y) * v1;
                    h = __expf(d4.z * A) * h + (d4.z * x4.z) * v2;
                    h = __expf(d4.w * A) * h + (d4.w * x4.w) * v3;
                    sd += d4.x + d4.y + d4.z + d4.w;
                }
                size_t idx = ((size_t)(bb * ED + e) * NSPAN + s) * NS + n;
                saL[idx] = __expf(A * sd);
                shL[idx] = h;
            }
        }
        gbar(layer * 3 + 1);

        // ================= SCAN P2: prefix fold + rescan + gate =============
        {
            const int gid = tid >> 5;
            const int n   = tid & 31;
            const int T   = (bN - b0) * ED * NSPAN;
            for (int g = lidx * 8 + gid; g < T; g += nwork * 8) {
                int bb = b0 + g / (ED * NSPAN);
                int r  = g % (ED * NSPAN);
                int e  = r >> 5;
                int s  = r & 31;
                float A  = -__expf(al[e * NS + n]);
                float Dv = dpp[e];

                // exclusive prefix over this chain's earlier span summaries
                float h = 0.f;
                size_t sbase = (size_t)(bb * ED + e) * NSPAN * NS + n;
                for (int sp = 0; sp < s; ++sp)
                    h = saL[sbase + sp * NS] * h + shL[sbase + sp * NS];

                size_t eRow = (size_t)(bb * ED + e) * L_ + s * SPANL;
                size_t nRow = ((size_t)bb * L_ + s * SPANL) * NS + n;
                const float4* dRow = (const float4*)(dL + eRow);
                const float4* xRow = (const float4*)(xcL + eRow);
                const float* bBase = BmL + nRow;
                const float* cBase = CmL + nRow;
                const float* zRow  = zL + eRow;
                float*       yRow  = yL + eRow;
                int s0 = n & 1, s1 = n & 2;
#pragma unroll 2
                for (int q = 0; q < SPANL / 4; ++q) {
                    float4 d4 = dRow[q];
                    float4 x4 = xRow[q];
                    float bb0 = bBase[(4 * q + 0) * NS];
                    float bb1 = bBase[(4 * q + 1) * NS];
                    float bb2 = bBase[(4 * q + 2) * NS];
                    float bb3 = bBase[(4 * q + 3) * NS];
                    float cc0 = cBase[(4 * q + 0) * NS];
                    float cc1 = cBase[(4 * q + 1) * NS];
                    float cc2 = cBase[(4 * q + 2) * NS];
                    float cc3 = cBase[(4 * q + 3) * NS];
                    h = __expf(d4.x * A) * h + (d4.x * x4.x) * bb0;  float p0 = h * cc0;
                    h = __expf(d4.y * A) * h + (d4.y * x4.y) * bb1;  float p1 = h * cc1;
                    h = __expf(d4.z * A) * h + (d4.z * x4.z) * bb2;  float p2 = h * cc2;
                    h = __expf(d4.w * A) * h + (d4.w * x4.w) * bb3;  float p3 = h * cc3;
                    // multi-value butterfly: lane n%4==k sums p_k over 32 lanes
                    float u  = s0 ? p1 : p0;
                    float us = s0 ? p0 : p1;
                    u += __shfl_xor(us, 1, 32);
                    float v  = s0 ? p3 : p2;
                    float vs = s0 ? p2 : p3;
                    v += __shfl_xor(vs, 1, 32);
                    float wv  = s1 ? v : u;
                    float wvs = s1 ? u : v;
                    wv += __shfl_xor(wvs, 2, 32);
                    wv += __shfl_xor(wv, 4, 32);
                    wv += __shfl_xor(wv, 8, 32);
                    wv += __shfl_xor(wv, 16, 32);
                    if (n < 4) {
                        int l4 = q * 4;
                        float xs = (n == 0) ? x4.x : (n == 1) ? x4.y
                                 : (n == 2) ? x4.z : x4.w;
                        float yr = wv + Dv * xs;
                        float zv = zRow[l4 + n];
                        yRow[l4 + n] = yr * (zv / (1.f + __expf(-zv)));
                    }
                }
            }
        }
        gbar(layer * 3 + 2);
    }

    // ================= classifier (per group, own batches only) =============
    {
        const float* y3 = ws + (size_t)3 * LSTRIDE + 3 * EDL;
        if (lidx == 0 && tid < NCLASSES) {
            int c = tid;
            for (int bb = b0; bb < bN; ++bb) {
                const float* yp = y3 + (size_t)bb * ED * L_ + (L_ - 1);
                const float* wp = fc_w + c * ED;
                float acc = fc_b[c];
#pragma unroll
                for (int e = 0; e < ED; ++e) acc += yp[(size_t)e * L_] * wp[e];
                out[bb * NCLASSES + c] = acc;
            }
        }
    }
}

// ---------------------------------------------------------------------------
extern "C" void kernel_launch(void* const* d_in, const int* in_sizes, int n_in,
                              void* d_out, int out_size, void* d_ws, size_t ws_size,
                              hipStream_t stream)
{
    const float* x          = (const float*)d_in[0];
    const float* in_proj_w  = (const float*)d_in[1];
    const float* conv_w     = (const float*)d_in[2];
    const float* conv_b     = (const float*)d_in[3];
    const float* x_proj_w   = (const float*)d_in[4];
    const float* dt_proj_w  = (const float*)d_in[5];
    const float* dt_proj_b  = (const float*)d_in[6];
    const float* A_log      = (const float*)d_in[7];
    const float* Dp         = (const float*)d_in[8];
    const float* out_proj_w = (const float*)d_in[9];
    const float* norm_w     = (const float*)d_in[10];
    const float* fc_w       = (const float*)d_in[11];
    const float* fc_b       = (const float*)d_in[12];
    float* ws = (float*)d_ws;

    // zero registration + barrier counters (graph-capturable memset node)
    hipMemsetAsync((void*)(ws + WS_BAR), 0, BAR_BYTES, stream);

    k_all<<<dim3(NBLK), dim3(256), 0, stream>>>(
        x, in_proj_w, conv_w, conv_b, x_proj_w, dt_proj_w, dt_proj_b,
        A_log, Dp, out_proj_w, norm_w, fc_w, fc_b, (float*)d_out, ws);
}